// Round 14
// baseline (534.849 us; speedup 1.0000x reference)
//
#include <hip/hip_runtime.h>

typedef short short8 __attribute__((ext_vector_type(8)));
typedef float f32x4 __attribute__((ext_vector_type(4)));
typedef float f32x2 __attribute__((ext_vector_type(2)));
typedef unsigned short u16;
typedef unsigned int u32;

__device__ __forceinline__ u32 cvt2(float a, float b) {
    u32 r; asm("v_cvt_pk_bf16_f32 %0, %1, %2" : "=v"(r) : "v"(a), "v"(b)); return r;
}
__device__ __forceinline__ u16 f2bf(float f) {
    u32 r; asm("v_cvt_pk_bf16_f32 %0, %1, %1" : "=v"(r) : "v"(f)); return (u16)r;
}
__device__ __forceinline__ float bf2f(u16 b) {
    union { u32 u; float f; } v; v.u = ((u32)b) << 16; return v.f;
}

// 16-lane butterfly sum of an (s,q) pair via DPP movs + packed f32 adds.
// 3 inst/step (2 mov_dpp + 1 v_pk_add_f32) vs 4 scalar.
__device__ __forceinline__ f32x2 dppadd16x2(f32x2 v) {
    union fi { float f; int i; };
    fi x, y, tx, ty;
    f32x2 t;
#define STEP(PAT) { \
    x.f = v.x; y.f = v.y; \
    tx.i = __builtin_amdgcn_update_dpp(0, x.i, PAT, 0xF, 0xF, true); \
    ty.i = __builtin_amdgcn_update_dpp(0, y.i, PAT, 0xF, 0xF, true); \
    t.x = tx.f; t.y = ty.f; \
    asm("v_pk_add_f32 %0, %1, %2" : "=v"(v) : "v"(v), "v"(t)); }
    STEP(0xB1) STEP(0x4E) STEP(0x141) STEP(0x140)
#undef STEP
    return v;
}

// One MLP layer: X (bf16 LDS [64][K+8]) @ Wt (bf16 global, row-stride WSTRIDE) + bias,
// row LayerNorm, opt SiLU.  NW waves, ALL active: wave w owns cols [w*N/NW,(w+1)*N/NW).
// B register double/triple-buffered from global; K-loop barrier-free; setprio(1) around
// MFMA bursts.  LN reduce: packed DPP butterfly -> one LDS atomic pair per row per wave.
// SINIT: acc init from SInit (bf16 LDS, stride SLD, bias pre-baked).
// OMODE 0: bf16 to Ol (stride N+8), trailing barrier.
// OMODE 1 (requires NT==1): fused global epilogue  gout = base + (degv? mask(h):h).
//   RESLDS: base = bf2f(residL[row*residLD+col]);  else base = resid prefetched pre-loop.
template<int K, int WSTRIDE, int N, int NW, bool SILU, bool SINIT, int OMODE, bool RESLDS>
__device__ __forceinline__ void mlp_layer(
    const u16* Xl, u16* Ol, const u16* SInit, int SLD,
    const u16* residL, int residLD,
    float* red_cur, float* red_next,
    const u16* __restrict__ Wt, const float* __restrict__ bias,
    const float* __restrict__ gamma, const float* __restrict__ beta,
    const float* resid, float* gout, u16* bout, const u32* degv, int rowsv)
{
    constexpr int LDX = K + 8;
    constexpr int LDO = N + 8;
    constexpr int NT = N / (16 * NW);
    constexpr int KS = K / 32;
    static_assert(N % (16 * NW) == 0 && NT >= 1 && (KS % 2) == 0, "bad split");
    static_assert(OMODE == 0 || NT == 1, "OMODE1 requires NT==1");
    const int tid = threadIdx.x;
    const int wave = tid >> 6;
    const int lane = tid & 63;
    const int l15 = lane & 15;
    const int lg = lane >> 4;
    const int nbase = wave * (N / NW);

    f32x4 acc[4][NT];
    float fres[16];   // OMODE1 !RESLDS residual prefetch

    const u16* wp[NT];
    #pragma unroll
    for (int nt = 0; nt < NT; ++nt)
        wp[nt] = Wt + (size_t)(nbase + nt * 16 + l15) * WSTRIDE + lg * 8;
    const u16* xp = Xl + l15 * LDX + lg * 8;

    if constexpr (OMODE == 1 && !RESLDS) {
        #pragma unroll
        for (int mt = 0; mt < 4; ++mt)
            #pragma unroll
            for (int r = 0; r < 4; ++r) {
                int row = mt * 16 + lg * 4 + r;
                fres[mt * 4 + r] = (row < rowsv) ? resid[row * 128 + nbase + l15] : 0.f;
            }
    }

    if constexpr (SINIT) {
        #pragma unroll
        for (int mt = 0; mt < 4; ++mt)
            #pragma unroll
            for (int r = 0; r < 4; ++r) {
                int row = mt * 16 + lg * 4 + r;
                #pragma unroll
                for (int nt = 0; nt < NT; ++nt)
                    acc[mt][nt][r] = bf2f(SInit[row * SLD + nbase + nt * 16 + l15]);
            }
    } else {
        #pragma unroll
        for (int mt = 0; mt < 4; ++mt)
            #pragma unroll
            for (int nt = 0; nt < NT; ++nt)
                acc[mt][nt] = (f32x4){0.f, 0.f, 0.f, 0.f};
    }

    short8 a[4];

#define BLOAD(ks, arr) { _Pragma("unroll") \
    for (int nt = 0; nt < NT; ++nt) arr[nt] = *(const short8*)(wp[nt] + (ks) * 32); }
#define ALOAD(ks) { _Pragma("unroll") \
    for (int mt = 0; mt < 4; ++mt) a[mt] = *(const short8*)(xp + mt * 16 * LDX + (ks) * 32); }
#define MFMAS(arr) { __builtin_amdgcn_s_setprio(1); _Pragma("unroll") \
    for (int nt = 0; nt < NT; ++nt) { _Pragma("unroll") \
        for (int mt = 0; mt < 4; ++mt) \
            acc[mt][nt] = __builtin_amdgcn_mfma_f32_16x16x32_bf16(a[mt], arr[nt], acc[mt][nt], 0, 0, 0); } \
    __builtin_amdgcn_s_setprio(0); }

    if (NT == 1) {
        short8 b0[NT], b1[NT], b2[NT];
        BLOAD(0, b0);
        BLOAD(1, b1);
        #pragma unroll
        for (int ks = 0; ks < KS; ++ks) {
            if (ks + 2 < KS) {
                if (ks % 3 == 0) { BLOAD(ks + 2, b2); }
                else if (ks % 3 == 1) { BLOAD(ks + 2, b0); }
                else { BLOAD(ks + 2, b1); }
            }
            ALOAD(ks);
            if (ks % 3 == 0) { MFMAS(b0); }
            else if (ks % 3 == 1) { MFMAS(b1); }
            else { MFMAS(b2); }
        }
    } else {
        short8 b0[NT], b1[NT];
        BLOAD(0, b0);
        #pragma unroll
        for (int ks = 0; ks < KS; ++ks) {
            if (ks + 1 < KS) {
                if (ks & 1) { BLOAD(ks + 1, b0); } else { BLOAD(ks + 1, b1); }
            }
            ALOAD(ks);
            if (ks & 1) { MFMAS(b1); } else { MFMAS(b0); }
        }
    }
#undef BLOAD
#undef ALOAD
#undef MFMAS

    float bv[NT];
    #pragma unroll
    for (int nt = 0; nt < NT; ++nt) bv[nt] = SINIT ? 0.f : bias[nbase + nt * 16 + l15];
    #pragma unroll
    for (int mt = 0; mt < 4; ++mt) {
        f32x2 sq0 = (f32x2){0.f, 0.f}, sq1 = sq0, sq2 = sq0, sq3 = sq0;
        #pragma unroll
        for (int nt = 0; nt < NT; ++nt) {
            float v0 = acc[mt][nt][0] + bv[nt]; acc[mt][nt][0] = v0;
            sq0.x += v0; sq0.y = fmaf(v0, v0, sq0.y);
            float v1 = acc[mt][nt][1] + bv[nt]; acc[mt][nt][1] = v1;
            sq1.x += v1; sq1.y = fmaf(v1, v1, sq1.y);
            float v2 = acc[mt][nt][2] + bv[nt]; acc[mt][nt][2] = v2;
            sq2.x += v2; sq2.y = fmaf(v2, v2, sq2.y);
            float v3 = acc[mt][nt][3] + bv[nt]; acc[mt][nt][3] = v3;
            sq3.x += v3; sq3.y = fmaf(v3, v3, sq3.y);
        }
        sq0 = dppadd16x2(sq0); sq1 = dppadd16x2(sq1);
        sq2 = dppadd16x2(sq2); sq3 = dppadd16x2(sq3);
        if (l15 == 0) {
            int row = mt * 16 + lg * 4;
            atomicAdd(&red_cur[(row + 0) * 2 + 0], sq0.x);
            atomicAdd(&red_cur[(row + 0) * 2 + 1], sq0.y);
            atomicAdd(&red_cur[(row + 1) * 2 + 0], sq1.x);
            atomicAdd(&red_cur[(row + 1) * 2 + 1], sq1.y);
            atomicAdd(&red_cur[(row + 2) * 2 + 0], sq2.x);
            atomicAdd(&red_cur[(row + 2) * 2 + 1], sq2.y);
            atomicAdd(&red_cur[(row + 3) * 2 + 0], sq3.x);
            atomicAdd(&red_cur[(row + 3) * 2 + 1], sq3.y);
        }
    }
    __syncthreads();                        // B1: partials complete; all X/S reads done
    if (tid < 128) red_next[tid] = 0.f;     // ping-pong buffer for next layer

    {
        float gv[NT], btv[NT];
        #pragma unroll
        for (int nt = 0; nt < NT; ++nt) {
            int n = nbase + nt * 16 + l15;
            gv[nt] = gamma[n]; btv[nt] = beta[n];
        }
        constexpr float invN = 1.f / (float)N;
        #pragma unroll
        for (int mt = 0; mt < 4; ++mt)
            #pragma unroll
            for (int r = 0; r < 4; ++r) {
                int row = mt * 16 + lg * 4 + r;
                float2 sq = *(const float2*)&red_cur[row * 2];
                float mean = sq.x * invN;
                float rstd = rsqrtf(fmaf(sq.y, invN, -mean * mean) + 1e-5f);
                #pragma unroll
                for (int nt = 0; nt < NT; ++nt) {
                    float am = rstd * gv[nt];
                    float h = fmaf(acc[mt][nt][r], am, fmaf(-mean, am, btv[nt]));
                    if (SILU) h = h * __builtin_amdgcn_rcpf(1.f + __expf(-h));
                    int col = nbase + nt * 16 + l15;
                    if constexpr (OMODE == 0) {
                        Ol[row * LDO + col] = f2bf(h);
                    } else {
                        if (row < rowsv) {
                            float base = RESLDS ? bf2f(residL[row * residLD + col])
                                                : fres[mt * 4 + r];
                            float val = h;
                            if (degv) val = (degv[row] > 0u) ? h : 0.f;
                            gout[row * 128 + col] = base + val;
                            if (bout) bout[row * 128 + col] = f2bf(h);
                        }
                    }
                }
            }
    }
    if constexpr (OMODE == 0) __syncthreads();   // B2: Ol visible (may alias Xl/SInit)
}

// ---------------- prep1: 6x weight transpose/cast + edge binning, one launch
__device__ __forceinline__ void wtr_body(const float* W, u16* Wt, int K, int N, int i) {
    if (i < K * N) {
        int k = i / N, n = i % N;
        Wt[(size_t)n * K + k] = f2bf(W[i]);
    }
}
__global__ __launch_bounds__(256) void prep1_kernel(
    const float* ew0, u16* ew0t, const float* ew1, u16* ew1t,
    const float* dw0, u16* dw0t, const float* dw1, u16* dw1t,
    const float* sw0, u16* sw0t, const float* sw1, u16* sw1t,
    const int* __restrict__ dst_idx, u32* __restrict__ cursor, int* __restrict__ elist, int E)
{
    const int bid = blockIdx.x;
    const int tid = threadIdx.x;
    if (bid < 576)       wtr_body(ew0, ew0t, 384, 384, bid * 256 + tid);
    else if (bid < 768)  wtr_body(ew1, ew1t, 384, 128, (bid - 576) * 256 + tid);
    else if (bid < 1024) wtr_body(dw0, dw0t, 256, 256, (bid - 768) * 256 + tid);
    else if (bid < 1152) wtr_body(dw1, dw1t, 256, 128, (bid - 1024) * 256 + tid);
    else if (bid < 1216) wtr_body(sw0, sw0t, 128, 128, (bid - 1152) * 256 + tid);
    else if (bid < 1280) wtr_body(sw1, sw1t, 128, 128, (bid - 1216) * 256 + tid);
    else {
        int e = (bid - 1280) * 256 + tid;
        if (e < E) {
            int d = dst_idx[e];
            u32 slot = atomicAdd(&cursor[d], 1u);
            if (slot < 64u) elist[(size_t)d * 64 + slot] = e;
        }
    }
}

// ---------------- prep2: both node-projection tables in one launch
__global__ __launch_bounds__(768, 6) void prep2_kernel(
    const float* __restrict__ h_src, const float* __restrict__ h_dst,
    const u16* __restrict__ ew0t, const float* __restrict__ eb0,
    u16* __restrict__ pre_src, u16* __restrict__ pre_dst, int NS, int ND, int nbS)
{
    __shared__ alignas(16) u16 Xl[64 * 136];
    const bool isS = (int)blockIdx.x < nbS;
    const float* Hin = isS ? h_src : h_dst;
    const u16* Wt = isS ? (ew0t + 128) : (ew0t + 256);
    const float* bias = isS ? eb0 : nullptr;
    u16* Pout = isS ? pre_src : pre_dst;
    const int M = isS ? NS : ND;
    const int nBase = (isS ? blockIdx.x : (blockIdx.x - nbS)) * 64;
    const int rowsM = min(64, M - nBase);
    const int tid = threadIdx.x;

    if (tid < 512) {
        const int row = tid >> 3, q8 = tid & 7;
        u16* xr = Xl + row * 136;
        if (row < rowsM) {
            const float* p = Hin + (size_t)(nBase + row) * 128;
            #pragma unroll
            for (int j = 0; j < 4; ++j) {
                int col = (q8 + j * 8) * 4;
                float4 v = *(const float4*)(p + col);
                *(uint2*)(xr + col) = make_uint2(cvt2(v.x, v.y), cvt2(v.z, v.w));
            }
        } else {
            #pragma unroll
            for (int j = 0; j < 4; ++j)
                *(uint2*)(xr + (q8 + j * 8) * 4) = make_uint2(0u, 0u);
        }
    }
    __syncthreads();

    const int wave = tid >> 6;
    const int lane = tid & 63;
    const int l15 = lane & 15;
    const int lg = lane >> 4;
    const int nbase = wave * 32;

    const u16* wp[2];
    #pragma unroll
    for (int nt = 0; nt < 2; ++nt)
        wp[nt] = Wt + (size_t)(nbase + nt * 16 + l15) * 384 + lg * 8;
    const u16* xp = Xl + l15 * 136 + lg * 8;

    f32x4 acc[4][2];
    #pragma unroll
    for (int mt = 0; mt < 4; ++mt)
        #pragma unroll
        for (int nt = 0; nt < 2; ++nt)
            acc[mt][nt] = (f32x4){0.f, 0.f, 0.f, 0.f};

    short8 a[4], b0[2], b1[2];
    #pragma unroll
    for (int nt = 0; nt < 2; ++nt) b0[nt] = *(const short8*)(wp[nt]);
    #pragma unroll
    for (int ks = 0; ks < 4; ++ks) {
        if (ks + 1 < 4) {
            #pragma unroll
            for (int nt = 0; nt < 2; ++nt) {
                if (ks & 1) b0[nt] = *(const short8*)(wp[nt] + (ks + 1) * 32);
                else        b1[nt] = *(const short8*)(wp[nt] + (ks + 1) * 32);
            }
        }
        #pragma unroll
        for (int mt = 0; mt < 4; ++mt)
            a[mt] = *(const short8*)(xp + mt * 16 * 136 + ks * 32);
        #pragma unroll
        for (int nt = 0; nt < 2; ++nt)
            #pragma unroll
            for (int mt = 0; mt < 4; ++mt)
                acc[mt][nt] = __builtin_amdgcn_mfma_f32_16x16x32_bf16(
                    a[mt], (ks & 1) ? b1[nt] : b0[nt], acc[mt][nt], 0, 0, 0);
    }

    float bv[2];
    #pragma unroll
    for (int nt = 0; nt < 2; ++nt) bv[nt] = bias ? bias[nbase + nt * 16 + l15] : 0.f;
    #pragma unroll
    for (int mt = 0; mt < 4; ++mt)
        #pragma unroll
        for (int r = 0; r < 4; ++r) {
            int row = mt * 16 + lg * 4 + r;
            if (row < rowsM) {
                #pragma unroll
                for (int nt = 0; nt < 2; ++nt)
                    Pout[(size_t)(nBase + row) * 384 + nbase + nt * 16 + l15] =
                        f2bf(acc[mt][nt][r] + bv[nt]);
            }
        }
}

// ---------------- main: edge blocks [0,nbE) + src blocks [nbE, nbE+nbS); 8 waves (512t)
template<bool PRE>
__global__ __launch_bounds__(512, 4) void main_kernel(
    const float* __restrict__ e_h, const float* __restrict__ h_src, const float* __restrict__ h_dst,
    const int* __restrict__ src_idx, const int* __restrict__ dst_idx,
    const u16* __restrict__ pre_src, const u16* __restrict__ pre_dst,
    const u16* __restrict__ ew0t, const float* __restrict__ eb0, const float* __restrict__ eg0, const float* __restrict__ ebt0,
    const u16* __restrict__ ew1t, const float* __restrict__ eb1, const float* __restrict__ eg1, const float* __restrict__ ebt1,
    const u16* __restrict__ sw0t, const float* __restrict__ sb0, const float* __restrict__ sg0, const float* __restrict__ sbt0,
    const u16* __restrict__ sw1t, const float* __restrict__ sb1, const float* __restrict__ sg1, const float* __restrict__ sbt1,
    u16* __restrict__ e_new, float* __restrict__ e_out,
    float* __restrict__ hs_out, int E, int NS, int nbE)
{
    constexpr int XW = PRE ? 136 : 392;
    __shared__ alignas(16) u16 Xbuf[64 * XW];
    __shared__ alignas(16) u16 Sbuf[PRE ? 64 * 392 : 16];
    __shared__ alignas(8) float red[2][128];
    const int tid = threadIdx.x;

    if ((int)blockIdx.x >= nbE) {
        // ---------- src body: h_src -> MLP(128->128->128), residual
        const int nBase = ((int)blockIdx.x - nbE) * 64;
        const int rowsv = min(64, NS - nBase);
        if (tid < 256) ((float*)red)[tid] = 0.f;
        {
            const int row = tid >> 3, q8 = tid & 7;
            int n = nBase + row;
            u16* xr = Xbuf + row * 136;
            #pragma unroll
            for (int j = 0; j < 4; ++j) {
                int col = (q8 + j * 8) * 4;
                float4 v = make_float4(0.f, 0.f, 0.f, 0.f);
                if (n < NS) v = *(const float4*)(h_src + (size_t)n * 128 + col);
                *(uint2*)(xr + col) = make_uint2(cvt2(v.x, v.y), cvt2(v.z, v.w));
            }
        }
        __syncthreads();
        mlp_layer<128, 128, 128, 8, true, false, 0, false>(
            Xbuf, Xbuf, nullptr, 0, nullptr, 0, red[0], red[1], sw0t, sb0, sg0, sbt0,
            nullptr, nullptr, nullptr, nullptr, rowsv);
        mlp_layer<128, 128, 128, 8, false, false, 1, false>(
            Xbuf, nullptr, nullptr, 0, nullptr, 0, red[1], red[0], sw1t, sb1, sg1, sbt1,
            h_src + (size_t)nBase * 128, hs_out + (size_t)nBase * 128,
            (u16*)nullptr, nullptr, rowsv);
        return;
    }

    // ---------- edge body
    const int eBase = blockIdx.x * 64;
    const int rowsv = min(64, E - eBase);
    if (tid < 256) ((float*)red)[tid] = 0.f;

    if constexpr (PRE) {
        // X = e_h (coalesced); 8 threads/row, 4 float4 each
        {
            const int row = tid >> 3, q8 = tid & 7;
            u16* xr = Xbuf + row * 136;
            if (row < rowsv) {
                const float* pe = e_h + (size_t)(eBase + row) * 128;
                #pragma unroll
                for (int j = 0; j < 4; ++j) {
                    int col = (q8 + j * 8) * 4;
                    float4 v = *(const float4*)(pe + col);
                    *(uint2*)(xr + col) = make_uint2(cvt2(v.x, v.y), cvt2(v.z, v.w));
                }
            } else {
                #pragma unroll
                for (int j = 0; j < 4; ++j)
                    *(uint2*)(xr + (q8 + j * 8) * 4) = make_uint2(0u, 0u);
            }
        }
        // S = pre_src[src]+pre_dst[dst]; 8 thr/row, 6 x 16B chunks each (u32 bit-trick)
        {
            const int row = tid >> 3, q8 = tid & 7;
            u16* sr = Sbuf + row * 392;
            if (row < rowsv) {
                int e = eBase + row;
                const u16* ps = pre_src + (size_t)src_idx[e] * 384;
                const u16* pd = pre_dst + (size_t)dst_idx[e] * 384;
                #pragma unroll
                for (int j = 0; j < 6; ++j) {
                    int c = (q8 + j * 8) * 8;            // 0..376
                    uint4 A4 = *(const uint4*)(ps + c);
                    uint4 B4 = *(const uint4*)(pd + c);
                    uint4 O4;
                    union { u32 u; float f; } al, ah, bl, bh;
                    al.u = A4.x << 16; ah.u = A4.x & 0xFFFF0000u;
                    bl.u = B4.x << 16; bh.u = B4.x & 0xFFFF0000u;
                    O4.x = cvt2(al.f + bl.f, ah.f + bh.f);
                    al.u = A4.y << 16; ah.u = A4.y & 0xFFFF0000u;
                    bl.u = B4.y << 16; bh.u = B4.y & 0xFFFF0000u;
                    O4.y = cvt2(al.f + bl.f, ah.f + bh.f);
                    al.u = A4.z << 16; ah.u = A4.z & 0xFFFF0000u;
                    bl.u = B4.z << 16; bh.u = B4.z & 0xFFFF0000u;
                    O4.z = cvt2(al.f + bl.f, ah.f + bh.f);
                    al.u = A4.w << 16; ah.u = A4.w & 0xFFFF0000u;
                    bl.u = B4.w << 16; bh.u = B4.w & 0xFFFF0000u;
                    O4.w = cvt2(al.f + bl.f, ah.f + bh.f);
                    *(uint4*)(sr + c) = O4;
                }
            } else {
                #pragma unroll
                for (int j = 0; j < 6; ++j)
                    *(uint4*)(sr + (q8 + j * 8) * 8) = make_uint4(0u, 0u, 0u, 0u);
            }
        }
        __syncthreads();

        // layer 1: K=128 (e_h block of W0), acc-init from S (bias baked into pre_src)
        mlp_layer<128, 384, 384, 8, true, true, 0, false>(
            Xbuf, Sbuf, Sbuf, 392, nullptr, 0, red[0], red[1], ew0t, nullptr, eg0, ebt0,
            nullptr, nullptr, nullptr, nullptr, rowsv);

        // layer 2: residual from LDS Xbuf (bf16 e_h intact) -> no HBM re-read
        mlp_layer<384, 384, 128, 8, false, false, 1, true>(
            Sbuf, nullptr, nullptr, 0, Xbuf, 136, red[1], red[0], ew1t, eb1, eg1, ebt1,
            nullptr, e_out + (size_t)eBase * 128,
            e_new ? e_new + (size_t)eBase * 128 : (u16*)nullptr, nullptr, rowsv);
    } else {
        // fallback: full concat staging, K=384 layer 1; 8 thr/row, 12 float4 each
        {
            const int row = tid >> 3, q8 = tid & 7;
            u16* xr = Xbuf + row * 392;
            if (row < rowsv) {
                int e = eBase + row;
                const float* pe = e_h   + (size_t)e * 128;
                const float* ps = h_src + (size_t)src_idx[e] * 128;
                const float* pd = h_dst + (size_t)dst_idx[e] * 128;
                #pragma unroll
                for (int j = 0; j < 12; ++j) {
                    int col = (q8 + j * 8) * 4;          // 0..380
                    const float* p = (col < 128) ? (pe + col)
                                   : (col < 256) ? (ps + col - 128)
                                                 : (pd + col - 256);
                    float4 v = *(const float4*)p;
                    *(uint2*)(xr + col) = make_uint2(cvt2(v.x, v.y), cvt2(v.z, v.w));
                }
            } else {
                #pragma unroll
                for (int j = 0; j < 12; ++j)
                    *(uint2*)(xr + (q8 + j * 8) * 4) = make_uint2(0u, 0u);
            }
        }
        __syncthreads();

        mlp_layer<384, 384, 384, 8, true, false, 0, false>(
            Xbuf, Xbuf, nullptr, 0, nullptr, 0, red[0], red[1], ew0t, eb0, eg0, ebt0,
            nullptr, nullptr, nullptr, nullptr, rowsv);

        mlp_layer<384, 384, 128, 8, false, false, 1, false>(
            Xbuf, nullptr, nullptr, 0, nullptr, 0, red[1], red[0], ew1t, eb1, eg1, ebt1,
            e_h + (size_t)eBase * 128, e_out + (size_t)eBase * 128,
            e_new ? e_new + (size_t)eBase * 128 : (u16*)nullptr, nullptr, rowsv);
    }
}

// ---------------- dst kernel: [h_dst | gather-sum(e_new)] -> MLP(256->256->128), deg mask, residual
__global__ __launch_bounds__(512, 6) void dst_kernel(
    const float* __restrict__ h_dst,
    const u16* __restrict__ e_new,
    const float* __restrict__ e_out, const float* __restrict__ e_h,   // fallback
    const int* __restrict__ elist, const u32* __restrict__ cursor,
    const u16* __restrict__ dw0t, const float* __restrict__ db0, const float* __restrict__ dg0, const float* __restrict__ dbt0,
    const u16* __restrict__ dw1t, const float* __restrict__ db1, const float* __restrict__ dg1, const float* __restrict__ dbt1,
    float* __restrict__ hd_out, int ND)
{
    __shared__ alignas(16) u16 Xbuf[64 * 264];
    __shared__ alignas(8) float red[2][128];
    const int tid = threadIdx.x;
    const int nBase = blockIdx.x * 64;
    const int rowsv = min(64, ND - nBase);

    if (tid < 256) ((float*)red)[tid] = 0.f;

    {
        const int row = tid >> 3, q8 = tid & 7;
        int n = nBase + row;
        u16* xr = Xbuf + row * 264;
        #pragma unroll
        for (int j = 0; j < 4; ++j) {
            int col = (q8 + j * 8) * 4;
            float4 v = make_float4(0.f, 0.f, 0.f, 0.f);
            if (n < ND) v = *(const float4*)(h_dst + (size_t)n * 128 + col);
            *(uint2*)(xr + col) = make_uint2(cvt2(v.x, v.y), cvt2(v.z, v.w));
        }
    }
    {
        const int r = tid >> 3, q = tid & 7;
        const int n = nBase + r;
        float accm[16];
        #pragma unroll
        for (int c = 0; c < 16; ++c) accm[c] = 0.f;
        if (n < ND) {
            int dg = min((int)cursor[n], 64);
            const int* el = elist + (size_t)n * 64;
            if (e_new) {
                for (int j = 0; j < dg; ++j) {
                    const u16* p = e_new + (size_t)el[j] * 128 + q * 16;
                    uint4 A4 = *(const uint4*)p;
                    uint4 B4 = *(const uint4*)(p + 8);
                    union { u32 u; float f; } lo, hi;
                    lo.u = A4.x << 16; hi.u = A4.x & 0xFFFF0000u;
                    accm[0] += lo.f;  accm[1] += hi.f;
                    lo.u = A4.y << 16; hi.u = A4.y & 0xFFFF0000u;
                    accm[2] += lo.f;  accm[3] += hi.f;
                    lo.u = A4.z << 16; hi.u = A4.z & 0xFFFF0000u;
                    accm[4] += lo.f;  accm[5] += hi.f;
                    lo.u = A4.w << 16; hi.u = A4.w & 0xFFFF0000u;
                    accm[6] += lo.f;  accm[7] += hi.f;
                    lo.u = B4.x << 16; hi.u = B4.x & 0xFFFF0000u;
                    accm[8] += lo.f;  accm[9] += hi.f;
                    lo.u = B4.y << 16; hi.u = B4.y & 0xFFFF0000u;
                    accm[10] += lo.f; accm[11] += hi.f;
                    lo.u = B4.z << 16; hi.u = B4.z & 0xFFFF0000u;
                    accm[12] += lo.f; accm[13] += hi.f;
                    lo.u = B4.w << 16; hi.u = B4.w & 0xFFFF0000u;
                    accm[14] += lo.f; accm[15] += hi.f;
                }
            } else {
                for (int j = 0; j < dg; ++j) {
                    const float* po = e_out + (size_t)el[j] * 128 + q * 16;
                    const float* ph = e_h  + (size_t)el[j] * 128 + q * 16;
                    #pragma unroll
                    for (int t = 0; t < 4; ++t) {
                        float4 vo = *(const float4*)(po + t * 4);
                        float4 vh = *(const float4*)(ph + t * 4);
                        accm[t * 4 + 0] += vo.x - vh.x;
                        accm[t * 4 + 1] += vo.y - vh.y;
                        accm[t * 4 + 2] += vo.z - vh.z;
                        accm[t * 4 + 3] += vo.w - vh.w;
                    }
                }
            }
        }
        #pragma unroll
        for (int c4 = 0; c4 < 4; ++c4)
            *(uint2*)(Xbuf + r * 264 + 128 + q * 16 + c4 * 4) =
                make_uint2(cvt2(accm[c4 * 4 + 0], accm[c4 * 4 + 1]),
                           cvt2(accm[c4 * 4 + 2], accm[c4 * 4 + 3]));
    }
    __syncthreads();

    mlp_layer<256, 256, 256, 8, true, false, 0, false>(
        Xbuf, Xbuf, nullptr, 0, nullptr, 0, red[0], red[1], dw0t, db0, dg0, dbt0,
        nullptr, nullptr, nullptr, nullptr, rowsv);

    mlp_layer<256, 256, 128, 8, false, false, 1, false>(
        Xbuf, nullptr, nullptr, 0, nullptr, 0, red[1], red[0], dw1t, db1, dg1, dbt1,
        h_dst + (size_t)nBase * 128, hd_out + (size_t)nBase * 128,
        (u16*)nullptr, cursor + nBase, rowsv);
}

extern "C" void kernel_launch(void* const* d_in, const int* in_sizes, int n_in,
                              void* d_out, int out_size, void* d_ws, size_t ws_size,
                              hipStream_t stream) {
    const float* e_h   = (const float*)d_in[0];
    const float* h_src = (const float*)d_in[1];
    const float* h_dst = (const float*)d_in[2];
    const int* src_idx = (const int*)d_in[3];
    const int* dst_idx = (const int*)d_in[4];
    const float* ew0 = (const float*)d_in[5];
    const float* eb0 = (const float*)d_in[6];
    const float* eg0 = (const float*)d_in[7];
    const float* ebt0 = (const float*)d_in[8];
    const float* ew1 = (const float*)d_in[9];
    const float* eb1 = (const float*)d_in[10];
    const float* eg1 = (const float*)d_in[11];
    const float* ebt1 = (const float*)d_in[12];
    const float* dw0 = (const float*)d_in[13];
    const float* db0 = (const float*)d_in[14];
    const float* dg0 = (const float*)d_in[15];
    const float* dbt0 = (const float*)d_in[16];
    const float* dw1 = (const float*)d_in[17];
    const float* db1 = (const float*)d_in[18];
    const float* dg1 = (const float*)d_in[19];
    const float* dbt1 = (const float*)d_in[20];
    const float* sw0 = (const float*)d_in[21];
    const float* sb0 = (const float*)d_in[22];
    const float* sg0 = (const float*)d_in[23];
    const float* sbt0 = (const float*)d_in[24];
    const float* sw1 = (const float*)d_in[25];
    const float* sb1 = (const float*)d_in[26];
    const float* sg1 = (const float*)d_in[27];
    const float* sbt1 = (const float*)d_in[28];

    const int E  = in_sizes[0] / 128;
    const int NS = in_sizes[1] / 128;
    const int ND = in_sizes[2] / 128;

    // workspace carve-up (16B-aligned chunks)
    char* ws = (char*)d_ws;
    size_t off = 0;
    int* elist = (int*)(ws + off);  off += (size_t)ND * 64 * 4;
    u32* cursor = (u32*)(ws + off); off += (size_t)ND * 4;
    u16* ew0t = (u16*)(ws + off);   off += (size_t)384 * 384 * 2;
    u16* ew1t = (u16*)(ws + off);   off += (size_t)128 * 384 * 2;
    u16* dw0t = (u16*)(ws + off);   off += (size_t)256 * 256 * 2;
    u16* dw1t = (u16*)(ws + off);   off += (size_t)128 * 256 * 2;
    u16* sw0t = (u16*)(ws + off);   off += (size_t)128 * 128 * 2;
    u16* sw1t = (u16*)(ws + off);   off += (size_t)128 * 128 * 2;

    size_t off_pre = off;
    u16* pre_src = (u16*)(ws + off); off += (size_t)NS * 384 * 2;
    u16* pre_dst = (u16*)(ws + off); off += (size_t)ND * 384 * 2;
    bool use_pre = (off <= ws_size);
    if (!use_pre) { off = off_pre; pre_src = nullptr; pre_dst = nullptr; }

    off = (off + 255) & ~(size_t)255;
    u16* e_new = (u16*)(ws + off);
    if (off + (size_t)E * 128 * 2 > ws_size) e_new = nullptr;

    hipMemsetAsync(cursor, 0, (size_t)ND * 4, stream);

    const int binBlocks = (E + 255) / 256;
    prep1_kernel<<<1280 + binBlocks, 256, 0, stream>>>(
        ew0, ew0t, ew1, ew1t, dw0, dw0t, dw1, dw1t, sw0, sw0t, sw1, sw1t,
        dst_idx, cursor, elist, E);

    const int nbE = (E + 63) / 64;
    const int nbS = (NS + 63) / 64;
    const int nbD = (ND + 63) / 64;

    if (use_pre)
        prep2_kernel<<<nbS + nbD, 768, 0, stream>>>(
            h_src, h_dst, ew0t, eb0, pre_src, pre_dst, NS, ND, nbS);

    float* e_out  = (float*)d_out;
    float* hs_out = e_out + (size_t)E * 128;
    float* hd_out = hs_out + (size_t)NS * 128;

    if (use_pre) {
        main_kernel<true><<<nbE + nbS, 512, 0, stream>>>(
            e_h, h_src, h_dst, src_idx, dst_idx, pre_src, pre_dst,
            ew0t, eb0, eg0, ebt0, ew1t, eb1, eg1, ebt1,
            sw0t, sb0, sg0, sbt0, sw1t, sb1, sg1, sbt1,
            e_new, e_out, hs_out, E, NS, nbE);
    } else {
        main_kernel<false><<<nbE + nbS, 512, 0, stream>>>(
            e_h, h_src, h_dst, src_idx, dst_idx, nullptr, nullptr,
            ew0t, eb0, eg0, ebt0, ew1t, eb1, eg1, ebt1,
            sw0t, sb0, sg0, sbt0, sw1t, sb1, sg1, sbt1,
            e_new, e_out, hs_out, E, NS, nbE);
    }

    dst_kernel<<<nbD, 512, 0, stream>>>(
        h_dst, e_new, e_out, e_h, elist, cursor,
        dw0t, db0, dg0, dbt0, dw1t, db1, dg1, dbt1,
        hd_out, ND);
}

// Round 15
// 523.793 us; speedup vs baseline: 1.0211x; 1.0211x over previous
//
#include <hip/hip_runtime.h>

typedef short short8 __attribute__((ext_vector_type(8)));
typedef float f32x4 __attribute__((ext_vector_type(4)));
typedef unsigned short u16;
typedef unsigned int u32;

__device__ __forceinline__ u32 cvt2(float a, float b) {
    u32 r; asm("v_cvt_pk_bf16_f32 %0, %1, %2" : "=v"(r) : "v"(a), "v"(b)); return r;
}
__device__ __forceinline__ u16 f2bf(float f) {
    u32 r; asm("v_cvt_pk_bf16_f32 %0, %1, %1" : "=v"(r) : "v"(f)); return (u16)r;
}
__device__ __forceinline__ float bf2f(u16 b) {
    union { u32 u; float f; } v; v.u = ((u32)b) << 16; return v.f;
}

// 16-lane butterfly sum via DPP (pure VALU, no LDS pipe).
__device__ __forceinline__ float dppadd16(float v) {
    union fi { float f; int i; };
    fi a, t; a.f = v;
    t.i = __builtin_amdgcn_update_dpp(0, a.i, 0xB1,  0xF, 0xF, true); a.f += t.f;
    t.i = __builtin_amdgcn_update_dpp(0, a.i, 0x4E,  0xF, 0xF, true); a.f += t.f;
    t.i = __builtin_amdgcn_update_dpp(0, a.i, 0x141, 0xF, 0xF, true); a.f += t.f;
    t.i = __builtin_amdgcn_update_dpp(0, a.i, 0x140, 0xF, 0xF, true); a.f += t.f;
    return a.f;
}

// One MLP layer: X (bf16 LDS [64][K+8]) @ Wt (bf16 global, row-stride WSTRIDE) + bias,
// row LayerNorm, opt SiLU.  NW waves, ALL active: wave w owns cols [w*N/NW,(w+1)*N/NW).
// B register double/triple-buffered from global; K-loop barrier-free; setprio(1) around
// MFMA bursts (waves drift out of phase -> role diversity, T5 applies).
// LN reduce: DPP butterfly (VALU) -> one LDS atomic per row per wave.
// SINIT: acc init from SInit (bf16 LDS, stride SLD, bias pre-baked).
// OMODE 0: bf16 to Ol (stride N+8), trailing barrier.
// OMODE 1 (requires NT==1): fused global epilogue  gout = base + (degv? mask(h):h).
//   RESLDS: base = bf2f(residL[row*residLD+col]);  else base = resid prefetched pre-loop.
template<int K, int WSTRIDE, int N, int NW, bool SILU, bool SINIT, int OMODE, bool RESLDS>
__device__ __forceinline__ void mlp_layer(
    const u16* Xl, u16* Ol, const u16* SInit, int SLD,
    const u16* residL, int residLD,
    float* red_cur, float* red_next,
    const u16* __restrict__ Wt, const float* __restrict__ bias,
    const float* __restrict__ gamma, const float* __restrict__ beta,
    const float* resid, float* gout, u16* bout, const u32* degv, int rowsv)
{
    constexpr int LDX = K + 8;
    constexpr int LDO = N + 8;
    constexpr int NT = N / (16 * NW);
    constexpr int KS = K / 32;
    static_assert(N % (16 * NW) == 0 && NT >= 1 && (KS % 2) == 0, "bad split");
    static_assert(OMODE == 0 || NT == 1, "OMODE1 requires NT==1");
    const int tid = threadIdx.x;
    const int wave = tid >> 6;
    const int lane = tid & 63;
    const int l15 = lane & 15;
    const int lg = lane >> 4;
    const int nbase = wave * (N / NW);

    f32x4 acc[4][NT];
    float fres[16];   // OMODE1 !RESLDS residual prefetch

    const u16* wp[NT];
    #pragma unroll
    for (int nt = 0; nt < NT; ++nt)
        wp[nt] = Wt + (size_t)(nbase + nt * 16 + l15) * WSTRIDE + lg * 8;
    const u16* xp = Xl + l15 * LDX + lg * 8;

    if constexpr (OMODE == 1 && !RESLDS) {
        #pragma unroll
        for (int mt = 0; mt < 4; ++mt)
            #pragma unroll
            for (int r = 0; r < 4; ++r) {
                int row = mt * 16 + lg * 4 + r;
                fres[mt * 4 + r] = (row < rowsv) ? resid[row * 128 + nbase + l15] : 0.f;
            }
    }

    if constexpr (SINIT) {
        #pragma unroll
        for (int mt = 0; mt < 4; ++mt)
            #pragma unroll
            for (int r = 0; r < 4; ++r) {
                int row = mt * 16 + lg * 4 + r;
                #pragma unroll
                for (int nt = 0; nt < NT; ++nt)
                    acc[mt][nt][r] = bf2f(SInit[row * SLD + nbase + nt * 16 + l15]);
            }
    } else {
        #pragma unroll
        for (int mt = 0; mt < 4; ++mt)
            #pragma unroll
            for (int nt = 0; nt < NT; ++nt)
                acc[mt][nt] = (f32x4){0.f, 0.f, 0.f, 0.f};
    }

    short8 a[4];

#define BLOAD(ks, arr) { _Pragma("unroll") \
    for (int nt = 0; nt < NT; ++nt) arr[nt] = *(const short8*)(wp[nt] + (ks) * 32); }
#define ALOAD(ks) { _Pragma("unroll") \
    for (int mt = 0; mt < 4; ++mt) a[mt] = *(const short8*)(xp + mt * 16 * LDX + (ks) * 32); }
#define MFMAS(arr) { __builtin_amdgcn_s_setprio(1); _Pragma("unroll") \
    for (int nt = 0; nt < NT; ++nt) { _Pragma("unroll") \
        for (int mt = 0; mt < 4; ++mt) \
            acc[mt][nt] = __builtin_amdgcn_mfma_f32_16x16x32_bf16(a[mt], arr[nt], acc[mt][nt], 0, 0, 0); } \
    __builtin_amdgcn_s_setprio(0); }

    if (NT == 1) {
        short8 b0[NT], b1[NT], b2[NT];
        BLOAD(0, b0);
        BLOAD(1, b1);
        #pragma unroll
        for (int ks = 0; ks < KS; ++ks) {
            if (ks + 2 < KS) {
                if (ks % 3 == 0) { BLOAD(ks + 2, b2); }
                else if (ks % 3 == 1) { BLOAD(ks + 2, b0); }
                else { BLOAD(ks + 2, b1); }
            }
            ALOAD(ks);
            if (ks % 3 == 0) { MFMAS(b0); }
            else if (ks % 3 == 1) { MFMAS(b1); }
            else { MFMAS(b2); }
        }
    } else {
        short8 b0[NT], b1[NT];
        BLOAD(0, b0);
        #pragma unroll
        for (int ks = 0; ks < KS; ++ks) {
            if (ks + 1 < KS) {
                if (ks & 1) { BLOAD(ks + 1, b0); } else { BLOAD(ks + 1, b1); }
            }
            ALOAD(ks);
            if (ks & 1) { MFMAS(b1); } else { MFMAS(b0); }
        }
    }
#undef BLOAD
#undef ALOAD
#undef MFMAS

    float bv[NT];
    #pragma unroll
    for (int nt = 0; nt < NT; ++nt) bv[nt] = SINIT ? 0.f : bias[nbase + nt * 16 + l15];
    #pragma unroll
    for (int mt = 0; mt < 4; ++mt) {
        float s[4] = {0.f, 0.f, 0.f, 0.f}, q[4] = {0.f, 0.f, 0.f, 0.f};
        #pragma unroll
        for (int nt = 0; nt < NT; ++nt)
            #pragma unroll
            for (int r = 0; r < 4; ++r) {
                float v = acc[mt][nt][r] + bv[nt];
                acc[mt][nt][r] = v;
                s[r] += v; q[r] = fmaf(v, v, q[r]);
            }
        #pragma unroll
        for (int r = 0; r < 4; ++r) {
            s[r] = dppadd16(s[r]);
            q[r] = dppadd16(q[r]);
        }
        if (l15 == 0) {
            int row = mt * 16 + lg * 4;
            #pragma unroll
            for (int r = 0; r < 4; ++r) {
                atomicAdd(&red_cur[(row + r) * 2 + 0], s[r]);
                atomicAdd(&red_cur[(row + r) * 2 + 1], q[r]);
            }
        }
    }
    __syncthreads();                        // B1: partials complete; all X/S reads done
    if (tid < 128) red_next[tid] = 0.f;     // ping-pong buffer for next layer

    {
        float gv[NT], btv[NT];
        #pragma unroll
        for (int nt = 0; nt < NT; ++nt) {
            int n = nbase + nt * 16 + l15;
            gv[nt] = gamma[n]; btv[nt] = beta[n];
        }
        constexpr float invN = 1.f / (float)N;
        #pragma unroll
        for (int mt = 0; mt < 4; ++mt)
            #pragma unroll
            for (int r = 0; r < 4; ++r) {
                int row = mt * 16 + lg * 4 + r;
                float2 sq = *(const float2*)&red_cur[row * 2];
                float mean = sq.x * invN;
                float rstd = rsqrtf(fmaf(sq.y, invN, -mean * mean) + 1e-5f);
                #pragma unroll
                for (int nt = 0; nt < NT; ++nt) {
                    float am = rstd * gv[nt];
                    float h = fmaf(acc[mt][nt][r], am, fmaf(-mean, am, btv[nt]));
                    if (SILU) h = h * __builtin_amdgcn_rcpf(1.f + __expf(-h));
                    int col = nbase + nt * 16 + l15;
                    if constexpr (OMODE == 0) {
                        Ol[row * LDO + col] = f2bf(h);
                    } else {
                        if (row < rowsv) {
                            float base = RESLDS ? bf2f(residL[row * residLD + col])
                                                : fres[mt * 4 + r];
                            float val = h;
                            if (degv) val = (degv[row] > 0u) ? h : 0.f;
                            gout[row * 128 + col] = base + val;
                            if (bout) bout[row * 128 + col] = f2bf(h);
                        }
                    }
                }
            }
    }
    if constexpr (OMODE == 0) __syncthreads();   // B2: Ol visible (may alias Xl/SInit)
}

// ---------------- prep1: 6x weight transpose/cast + edge binning, one launch
__device__ __forceinline__ void wtr_body(const float* W, u16* Wt, int K, int N, int i) {
    if (i < K * N) {
        int k = i / N, n = i % N;
        Wt[(size_t)n * K + k] = f2bf(W[i]);
    }
}
__global__ __launch_bounds__(256) void prep1_kernel(
    const float* ew0, u16* ew0t, const float* ew1, u16* ew1t,
    const float* dw0, u16* dw0t, const float* dw1, u16* dw1t,
    const float* sw0, u16* sw0t, const float* sw1, u16* sw1t,
    const int* __restrict__ dst_idx, u32* __restrict__ cursor, int* __restrict__ elist, int E)
{
    const int bid = blockIdx.x;
    const int tid = threadIdx.x;
    if (bid < 576)       wtr_body(ew0, ew0t, 384, 384, bid * 256 + tid);
    else if (bid < 768)  wtr_body(ew1, ew1t, 384, 128, (bid - 576) * 256 + tid);
    else if (bid < 1024) wtr_body(dw0, dw0t, 256, 256, (bid - 768) * 256 + tid);
    else if (bid < 1152) wtr_body(dw1, dw1t, 256, 128, (bid - 1024) * 256 + tid);
    else if (bid < 1216) wtr_body(sw0, sw0t, 128, 128, (bid - 1152) * 256 + tid);
    else if (bid < 1280) wtr_body(sw1, sw1t, 128, 128, (bid - 1216) * 256 + tid);
    else {
        int e = (bid - 1280) * 256 + tid;
        if (e < E) {
            int d = dst_idx[e];
            u32 slot = atomicAdd(&cursor[d], 1u);
            if (slot < 64u) elist[(size_t)d * 64 + slot] = e;
        }
    }
}

// ---------------- prep2: both node-projection tables in one launch
__global__ __launch_bounds__(768, 6) void prep2_kernel(
    const float* __restrict__ h_src, const float* __restrict__ h_dst,
    const u16* __restrict__ ew0t, const float* __restrict__ eb0,
    u16* __restrict__ pre_src, u16* __restrict__ pre_dst, int NS, int ND, int nbS)
{
    __shared__ alignas(16) u16 Xl[64 * 136];
    const bool isS = (int)blockIdx.x < nbS;
    const float* Hin = isS ? h_src : h_dst;
    const u16* Wt = isS ? (ew0t + 128) : (ew0t + 256);
    const float* bias = isS ? eb0 : nullptr;
    u16* Pout = isS ? pre_src : pre_dst;
    const int M = isS ? NS : ND;
    const int nBase = (isS ? blockIdx.x : (blockIdx.x - nbS)) * 64;
    const int rowsM = min(64, M - nBase);
    const int tid = threadIdx.x;

    if (tid < 512) {
        const int row = tid >> 3, q8 = tid & 7;
        u16* xr = Xl + row * 136;
        if (row < rowsM) {
            const float* p = Hin + (size_t)(nBase + row) * 128;
            #pragma unroll
            for (int j = 0; j < 4; ++j) {
                int col = (q8 + j * 8) * 4;
                float4 v = *(const float4*)(p + col);
                *(uint2*)(xr + col) = make_uint2(cvt2(v.x, v.y), cvt2(v.z, v.w));
            }
        } else {
            #pragma unroll
            for (int j = 0; j < 4; ++j)
                *(uint2*)(xr + (q8 + j * 8) * 4) = make_uint2(0u, 0u);
        }
    }
    __syncthreads();

    const int wave = tid >> 6;
    const int lane = tid & 63;
    const int l15 = lane & 15;
    const int lg = lane >> 4;
    const int nbase = wave * 32;

    const u16* wp[2];
    #pragma unroll
    for (int nt = 0; nt < 2; ++nt)
        wp[nt] = Wt + (size_t)(nbase + nt * 16 + l15) * 384 + lg * 8;
    const u16* xp = Xl + l15 * 136 + lg * 8;

    f32x4 acc[4][2];
    #pragma unroll
    for (int mt = 0; mt < 4; ++mt)
        #pragma unroll
        for (int nt = 0; nt < 2; ++nt)
            acc[mt][nt] = (f32x4){0.f, 0.f, 0.f, 0.f};

    short8 a[4], b0[2], b1[2];
    #pragma unroll
    for (int nt = 0; nt < 2; ++nt) b0[nt] = *(const short8*)(wp[nt]);
    #pragma unroll
    for (int ks = 0; ks < 4; ++ks) {
        if (ks + 1 < 4) {
            #pragma unroll
            for (int nt = 0; nt < 2; ++nt) {
                if (ks & 1) b0[nt] = *(const short8*)(wp[nt] + (ks + 1) * 32);
                else        b1[nt] = *(const short8*)(wp[nt] + (ks + 1) * 32);
            }
        }
        #pragma unroll
        for (int mt = 0; mt < 4; ++mt)
            a[mt] = *(const short8*)(xp + mt * 16 * 136 + ks * 32);
        #pragma unroll
        for (int nt = 0; nt < 2; ++nt)
            #pragma unroll
            for (int mt = 0; mt < 4; ++mt)
                acc[mt][nt] = __builtin_amdgcn_mfma_f32_16x16x32_bf16(
                    a[mt], (ks & 1) ? b1[nt] : b0[nt], acc[mt][nt], 0, 0, 0);
    }

    float bv[2];
    #pragma unroll
    for (int nt = 0; nt < 2; ++nt) bv[nt] = bias ? bias[nbase + nt * 16 + l15] : 0.f;
    #pragma unroll
    for (int mt = 0; mt < 4; ++mt)
        #pragma unroll
        for (int r = 0; r < 4; ++r) {
            int row = mt * 16 + lg * 4 + r;
            if (row < rowsM) {
                #pragma unroll
                for (int nt = 0; nt < 2; ++nt)
                    Pout[(size_t)(nBase + row) * 384 + nbase + nt * 16 + l15] =
                        f2bf(acc[mt][nt][r] + bv[nt]);
            }
        }
}

// ---------------- main: edge blocks [0,nbE) + src blocks [nbE, nbE+nbS); 8 waves (512t)
template<bool PRE>
__global__ __launch_bounds__(512, 4) void main_kernel(
    const float* __restrict__ e_h, const float* __restrict__ h_src, const float* __restrict__ h_dst,
    const int* __restrict__ src_idx, const int* __restrict__ dst_idx,
    const u16* __restrict__ pre_src, const u16* __restrict__ pre_dst,
    const u16* __restrict__ ew0t, const float* __restrict__ eb0, const float* __restrict__ eg0, const float* __restrict__ ebt0,
    const u16* __restrict__ ew1t, const float* __restrict__ eb1, const float* __restrict__ eg1, const float* __restrict__ ebt1,
    const u16* __restrict__ sw0t, const float* __restrict__ sb0, const float* __restrict__ sg0, const float* __restrict__ sbt0,
    const u16* __restrict__ sw1t, const float* __restrict__ sb1, const float* __restrict__ sg1, const float* __restrict__ sbt1,
    u16* __restrict__ e_new, float* __restrict__ e_out,
    float* __restrict__ hs_out, int E, int NS, int nbE)
{
    constexpr int XW = PRE ? 136 : 392;
    __shared__ alignas(16) u16 Xbuf[64 * XW];
    __shared__ alignas(16) u16 Sbuf[PRE ? 64 * 392 : 16];
    __shared__ alignas(8) float red[2][128];
    const int tid = threadIdx.x;

    if ((int)blockIdx.x >= nbE) {
        // ---------- src body: h_src -> MLP(128->128->128), residual
        const int nBase = ((int)blockIdx.x - nbE) * 64;
        const int rowsv = min(64, NS - nBase);
        if (tid < 256) ((float*)red)[tid] = 0.f;
        {
            const int row = tid >> 3, q8 = tid & 7;
            int n = nBase + row;
            u16* xr = Xbuf + row * 136;
            #pragma unroll
            for (int j = 0; j < 4; ++j) {
                int col = (q8 + j * 8) * 4;
                float4 v = make_float4(0.f, 0.f, 0.f, 0.f);
                if (n < NS) v = *(const float4*)(h_src + (size_t)n * 128 + col);
                *(uint2*)(xr + col) = make_uint2(cvt2(v.x, v.y), cvt2(v.z, v.w));
            }
        }
        __syncthreads();
        mlp_layer<128, 128, 128, 8, true, false, 0, false>(
            Xbuf, Xbuf, nullptr, 0, nullptr, 0, red[0], red[1], sw0t, sb0, sg0, sbt0,
            nullptr, nullptr, nullptr, nullptr, rowsv);
        mlp_layer<128, 128, 128, 8, false, false, 1, false>(
            Xbuf, nullptr, nullptr, 0, nullptr, 0, red[1], red[0], sw1t, sb1, sg1, sbt1,
            h_src + (size_t)nBase * 128, hs_out + (size_t)nBase * 128,
            (u16*)nullptr, nullptr, rowsv);
        return;
    }

    // ---------- edge body
    const int eBase = blockIdx.x * 64;
    const int rowsv = min(64, E - eBase);
    if (tid < 256) ((float*)red)[tid] = 0.f;

    if constexpr (PRE) {
        // X = e_h (coalesced); 8 threads/row, 4 float4 each
        {
            const int row = tid >> 3, q8 = tid & 7;
            u16* xr = Xbuf + row * 136;
            if (row < rowsv) {
                const float* pe = e_h + (size_t)(eBase + row) * 128;
                #pragma unroll
                for (int j = 0; j < 4; ++j) {
                    int col = (q8 + j * 8) * 4;
                    float4 v = *(const float4*)(pe + col);
                    *(uint2*)(xr + col) = make_uint2(cvt2(v.x, v.y), cvt2(v.z, v.w));
                }
            } else {
                #pragma unroll
                for (int j = 0; j < 4; ++j)
                    *(uint2*)(xr + (q8 + j * 8) * 4) = make_uint2(0u, 0u);
            }
        }
        // S = pre_src[src]+pre_dst[dst]; 8 thr/row, 6 x 16B chunks each
        {
            const int row = tid >> 3, q8 = tid & 7;
            u16* sr = Sbuf + row * 392;
            if (row < rowsv) {
                int e = eBase + row;
                const u16* ps = pre_src + (size_t)src_idx[e] * 384;
                const u16* pd = pre_dst + (size_t)dst_idx[e] * 384;
                #pragma unroll
                for (int j = 0; j < 6; ++j) {
                    int c = (q8 + j * 8) * 8;            // 0..376
                    short8 va = *(const short8*)(ps + c);
                    short8 vb = *(const short8*)(pd + c);
                    union { short8 s; u32 w[4]; } o;
                    #pragma unroll
                    for (int t = 0; t < 4; ++t) {
                        float f0 = bf2f((u16)va[2 * t])     + bf2f((u16)vb[2 * t]);
                        float f1 = bf2f((u16)va[2 * t + 1]) + bf2f((u16)vb[2 * t + 1]);
                        o.w[t] = cvt2(f0, f1);
                    }
                    *(short8*)(sr + c) = o.s;
                }
            } else {
                #pragma unroll
                for (int j = 0; j < 6; ++j)
                    *(short8*)(sr + (q8 + j * 8) * 8) = (short8){0,0,0,0,0,0,0,0};
            }
        }
        __syncthreads();

        // layer 1: K=128 (e_h block of W0), acc-init from S (bias baked into pre_src)
        mlp_layer<128, 384, 384, 8, true, true, 0, false>(
            Xbuf, Sbuf, Sbuf, 392, nullptr, 0, red[0], red[1], ew0t, nullptr, eg0, ebt0,
            nullptr, nullptr, nullptr, nullptr, rowsv);

        // layer 2: residual from LDS Xbuf (bf16 e_h intact) -> no HBM re-read
        mlp_layer<384, 384, 128, 8, false, false, 1, true>(
            Sbuf, nullptr, nullptr, 0, Xbuf, 136, red[1], red[0], ew1t, eb1, eg1, ebt1,
            nullptr, e_out + (size_t)eBase * 128,
            e_new ? e_new + (size_t)eBase * 128 : (u16*)nullptr, nullptr, rowsv);
    } else {
        // fallback: full concat staging, K=384 layer 1; 8 thr/row, 12 float4 each
        {
            const int row = tid >> 3, q8 = tid & 7;
            u16* xr = Xbuf + row * 392;
            if (row < rowsv) {
                int e = eBase + row;
                const float* pe = e_h   + (size_t)e * 128;
                const float* ps = h_src + (size_t)src_idx[e] * 128;
                const float* pd = h_dst + (size_t)dst_idx[e] * 128;
                #pragma unroll
                for (int j = 0; j < 12; ++j) {
                    int col = (q8 + j * 8) * 4;          // 0..380
                    const float* p = (col < 128) ? (pe + col)
                                   : (col < 256) ? (ps + col - 128)
                                                 : (pd + col - 256);
                    float4 v = *(const float4*)p;
                    *(uint2*)(xr + col) = make_uint2(cvt2(v.x, v.y), cvt2(v.z, v.w));
                }
            } else {
                #pragma unroll
                for (int j = 0; j < 12; ++j)
                    *(uint2*)(xr + (q8 + j * 8) * 4) = make_uint2(0u, 0u);
            }
        }
        __syncthreads();

        mlp_layer<384, 384, 384, 8, true, false, 0, false>(
            Xbuf, Xbuf, nullptr, 0, nullptr, 0, red[0], red[1], ew0t, eb0, eg0, ebt0,
            nullptr, nullptr, nullptr, nullptr, rowsv);

        mlp_layer<384, 384, 128, 8, false, false, 1, false>(
            Xbuf, nullptr, nullptr, 0, nullptr, 0, red[1], red[0], ew1t, eb1, eg1, ebt1,
            e_h + (size_t)eBase * 128, e_out + (size_t)eBase * 128,
            e_new ? e_new + (size_t)eBase * 128 : (u16*)nullptr, nullptr, rowsv);
    }
}

// ---------------- dst kernel: [h_dst | gather-sum(e_new)] -> MLP(256->256->128), deg mask, residual
__global__ __launch_bounds__(512, 6) void dst_kernel(
    const float* __restrict__ h_dst,
    const u16* __restrict__ e_new,
    const float* __restrict__ e_out, const float* __restrict__ e_h,   // fallback
    const int* __restrict__ elist, const u32* __restrict__ cursor,
    const u16* __restrict__ dw0t, const float* __restrict__ db0, const float* __restrict__ dg0, const float* __restrict__ dbt0,
    const u16* __restrict__ dw1t, const float* __restrict__ db1, const float* __restrict__ dg1, const float* __restrict__ dbt1,
    float* __restrict__ hd_out, int ND)
{
    __shared__ alignas(16) u16 Xbuf[64 * 264];
    __shared__ alignas(8) float red[2][128];
    const int tid = threadIdx.x;
    const int nBase = blockIdx.x * 64;
    const int rowsv = min(64, ND - nBase);

    if (tid < 256) ((float*)red)[tid] = 0.f;

    {
        const int row = tid >> 3, q8 = tid & 7;
        int n = nBase + row;
        u16* xr = Xbuf + row * 264;
        #pragma unroll
        for (int j = 0; j < 4; ++j) {
            int col = (q8 + j * 8) * 4;
            float4 v = make_float4(0.f, 0.f, 0.f, 0.f);
            if (n < ND) v = *(const float4*)(h_dst + (size_t)n * 128 + col);
            *(uint2*)(xr + col) = make_uint2(cvt2(v.x, v.y), cvt2(v.z, v.w));
        }
    }
    {
        const int r = tid >> 3, q = tid & 7;
        const int n = nBase + r;
        float accm[16];
        #pragma unroll
        for (int c = 0; c < 16; ++c) accm[c] = 0.f;
        if (n < ND) {
            int dg = min((int)cursor[n], 64);
            const int* el = elist + (size_t)n * 64;
            if (e_new) {
                for (int j = 0; j < dg; ++j) {
                    const u16* p = e_new + (size_t)el[j] * 128 + q * 16;
                    #pragma unroll
                    for (int t = 0; t < 2; ++t) {
                        short8 v = *(const short8*)(p + t * 8);
                        #pragma unroll
                        for (int c = 0; c < 8; ++c) accm[t * 8 + c] += bf2f((u16)v[c]);
                    }
                }
            } else {
                for (int j = 0; j < dg; ++j) {
                    const float* po = e_out + (size_t)el[j] * 128 + q * 16;
                    const float* ph = e_h  + (size_t)el[j] * 128 + q * 16;
                    #pragma unroll
                    for (int t = 0; t < 4; ++t) {
                        float4 vo = *(const float4*)(po + t * 4);
                        float4 vh = *(const float4*)(ph + t * 4);
                        accm[t * 4 + 0] += vo.x - vh.x;
                        accm[t * 4 + 1] += vo.y - vh.y;
                        accm[t * 4 + 2] += vo.z - vh.z;
                        accm[t * 4 + 3] += vo.w - vh.w;
                    }
                }
            }
        }
        #pragma unroll
        for (int c4 = 0; c4 < 4; ++c4)
            *(uint2*)(Xbuf + r * 264 + 128 + q * 16 + c4 * 4) =
                make_uint2(cvt2(accm[c4 * 4 + 0], accm[c4 * 4 + 1]),
                           cvt2(accm[c4 * 4 + 2], accm[c4 * 4 + 3]));
    }
    __syncthreads();

    mlp_layer<256, 256, 256, 8, true, false, 0, false>(
        Xbuf, Xbuf, nullptr, 0, nullptr, 0, red[0], red[1], dw0t, db0, dg0, dbt0,
        nullptr, nullptr, nullptr, nullptr, rowsv);

    mlp_layer<256, 256, 128, 8, false, false, 1, false>(
        Xbuf, nullptr, nullptr, 0, nullptr, 0, red[1], red[0], dw1t, db1, dg1, dbt1,
        h_dst + (size_t)nBase * 128, hd_out + (size_t)nBase * 128,
        (u16*)nullptr, cursor + nBase, rowsv);
}

extern "C" void kernel_launch(void* const* d_in, const int* in_sizes, int n_in,
                              void* d_out, int out_size, void* d_ws, size_t ws_size,
                              hipStream_t stream) {
    const float* e_h   = (const float*)d_in[0];
    const float* h_src = (const float*)d_in[1];
    const float* h_dst = (const float*)d_in[2];
    const int* src_idx = (const int*)d_in[3];
    const int* dst_idx = (const int*)d_in[4];
    const float* ew0 = (const float*)d_in[5];
    const float* eb0 = (const float*)d_in[6];
    const float* eg0 = (const float*)d_in[7];
    const float* ebt0 = (const float*)d_in[8];
    const float* ew1 = (const float*)d_in[9];
    const float* eb1 = (const float*)d_in[10];
    const float* eg1 = (const float*)d_in[11];
    const float* ebt1 = (const float*)d_in[12];
    const float* dw0 = (const float*)d_in[13];
    const float* db0 = (const float*)d_in[14];
    const float* dg0 = (const float*)d_in[15];
    const float* dbt0 = (const float*)d_in[16];
    const float* dw1 = (const float*)d_in[17];
    const float* db1 = (const float*)d_in[18];
    const float* dg1 = (const float*)d_in[19];
    const float* dbt1 = (const float*)d_in[20];
    const float* sw0 = (const float*)d_in[21];
    const float* sb0 = (const float*)d_in[22];
    const float* sg0 = (const float*)d_in[23];
    const float* sbt0 = (const float*)d_in[24];
    const float* sw1 = (const float*)d_in[25];
    const float* sb1 = (const float*)d_in[26];
    const float* sg1 = (const float*)d_in[27];
    const float* sbt1 = (const float*)d_in[28];

    const int E  = in_sizes[0] / 128;
    const int NS = in_sizes[1] / 128;
    const int ND = in_sizes[2] / 128;

    // workspace carve-up (16B-aligned chunks)
    char* ws = (char*)d_ws;
    size_t off = 0;
    int* elist = (int*)(ws + off);  off += (size_t)ND * 64 * 4;
    u32* cursor = (u32*)(ws + off); off += (size_t)ND * 4;
    u16* ew0t = (u16*)(ws + off);   off += (size_t)384 * 384 * 2;
    u16* ew1t = (u16*)(ws + off);   off += (size_t)128 * 384 * 2;
    u16* dw0t = (u16*)(ws + off);   off += (size_t)256 * 256 * 2;
    u16* dw1t = (u16*)(ws + off);   off += (size_t)128 * 256 * 2;
    u16* sw0t = (u16*)(ws + off);   off += (size_t)128 * 128 * 2;
    u16* sw1t = (u16*)(ws + off);   off += (size_t)128 * 128 * 2;

    size_t off_pre = off;
    u16* pre_src = (u16*)(ws + off); off += (size_t)NS * 384 * 2;
    u16* pre_dst = (u16*)(ws + off); off += (size_t)ND * 384 * 2;
    bool use_pre = (off <= ws_size);
    if (!use_pre) { off = off_pre; pre_src = nullptr; pre_dst = nullptr; }

    off = (off + 255) & ~(size_t)255;
    u16* e_new = (u16*)(ws + off);
    if (off + (size_t)E * 128 * 2 > ws_size) e_new = nullptr;

    hipMemsetAsync(cursor, 0, (size_t)ND * 4, stream);

    const int binBlocks = (E + 255) / 256;
    prep1_kernel<<<1280 + binBlocks, 256, 0, stream>>>(
        ew0, ew0t, ew1, ew1t, dw0, dw0t, dw1, dw1t, sw0, sw0t, sw1, sw1t,
        dst_idx, cursor, elist, E);

    const int nbE = (E + 63) / 64;
    const int nbS = (NS + 63) / 64;
    const int nbD = (ND + 63) / 64;

    if (use_pre)
        prep2_kernel<<<nbS + nbD, 768, 0, stream>>>(
            h_src, h_dst, ew0t, eb0, pre_src, pre_dst, NS, ND, nbS);

    float* e_out  = (float*)d_out;
    float* hs_out = e_out + (size_t)E * 128;
    float* hd_out = hs_out + (size_t)NS * 128;

    if (use_pre) {
        main_kernel<true><<<nbE + nbS, 512, 0, stream>>>(
            e_h, h_src, h_dst, src_idx, dst_idx, pre_src, pre_dst,
            ew0t, eb0, eg0, ebt0, ew1t, eb1, eg1, ebt1,
            sw0t, sb0, sg0, sbt0, sw1t, sb1, sg1, sbt1,
            e_new, e_out, hs_out, E, NS, nbE);
    } else {
        main_kernel<false><<<nbE + nbS, 512, 0, stream>>>(
            e_h, h_src, h_dst, src_idx, dst_idx, nullptr, nullptr,
            ew0t, eb0, eg0, ebt0, ew1t, eb1, eg1, ebt1,
            sw0t, sb0, sg0, sbt0, sw1t, sb1, sg1, sbt1,
            e_new, e_out, hs_out, E, NS, nbE);
    }

    dst_kernel<<<nbD, 512, 0, stream>>>(
        h_dst, e_new, e_out, e_h, elist, cursor,
        dw0t, db0, dg0, dbt0, dw1t, db1, dg1, dbt1,
        hd_out, ND);
}